// Round 1
// baseline (2506.299 us; speedup 1.0000x reference)
//
#include <hip/hip_runtime.h>

#define WPB 4   // waves per block (blockDim = 256)

// broadcast lane k's value to all lanes (static k -> v_readlane imm, SGPR operand to FMA)
__device__ __forceinline__ float bcastf(float v, int k) {
    return __int_as_float(__builtin_amdgcn_readlane(__float_as_int(v), k));
}

// One level of the tree GRNN.
// LEAF=true: ein points at contents8 (rows are 32-wide), child embeddings are
//            computed on the fly as relu(x @ Wu + bu)  (fuses level 8).
// LEAF=false: ein points at emb_{j+1} (rows are 64-wide), gathered directly.
template<bool LEAF>
__global__ __launch_bounds__(256, 2)
void grnn_level(const float* __restrict__ cont,   // n x 32
                const int*   __restrict__ child,  // n x 2
                const float* __restrict__ ein,    // emb_{j+1} (n2 x 64) or contents8 (n8 x 32)
                const float* __restrict__ Wu,     // 32 x 64
                const float* __restrict__ bu,     // 64
                const float* __restrict__ Wh,     // 192 x 64
                const float* __restrict__ bh,     // 64
                float* __restrict__ eout,         // n x 64
                int n)
{
    const int lane = threadIdx.x & 63;
    const int wid  = threadIdx.x >> 6;

    // per-lane weight columns, kept in registers (all indexing static)
    float wu[32];
#pragma unroll
    for (int k = 0; k < 32; ++k) wu[k] = Wu[k * 64 + lane];
    float w0[64], w1[64], w2[64];
#pragma unroll
    for (int k = 0; k < 64; ++k) w0[k] = Wh[k * 64 + lane];
#pragma unroll
    for (int k = 0; k < 64; ++k) w1[k] = Wh[(k + 64) * 64 + lane];
#pragma unroll
    for (int k = 0; k < 64; ++k) w2[k] = Wh[(k + 128) * 64 + lane];
    const float bul = bu[lane];
    const float bhl = bh[lane];
    const int   xl  = lane & 31;

    const int stride = gridDim.x * WPB;
    for (int r = blockIdx.x * WPB + wid; r < n; r += stride) {
        const int cx = child[2 * r];
        const int cy = child[2 * r + 1];

        float hLv, hRv;
        if (LEAF) {
            // recompute u8 rows on the fly: relu(contents8[c] @ Wu + bu)
            const float xLv = ein[cx * 32 + xl];   // lane<32 holds x[lane], 32..63 duplicate
            const float xRv = ein[cy * 32 + xl];
            float aL = bul, aR = bul;
#pragma unroll
            for (int k = 0; k < 32; ++k) {
                aL += bcastf(xLv, k) * wu[k];
                aR += bcastf(xRv, k) * wu[k];
            }
            hLv = fmaxf(aL, 0.f);
            hRv = fmaxf(aR, 0.f);
        } else {
            hLv = ein[cx * 64 + lane];
            hRv = ein[cy * 64 + lane];
        }

        // u = relu(x @ Wu + bu)
        const float xv = cont[r * 32 + xl];
        float au = bul;
#pragma unroll
        for (int k = 0; k < 32; ++k) au += bcastf(xv, k) * wu[k];
        const float uv = fmaxf(au, 0.f);

        // emb = relu([hL | hR | u] @ Wh + bh)
        float acc = bhl;
#pragma unroll
        for (int k = 0; k < 64; ++k) acc += bcastf(hLv, k) * w0[k];
#pragma unroll
        for (int k = 0; k < 64; ++k) acc += bcastf(hRv, k) * w1[k];
#pragma unroll
        for (int k = 0; k < 64; ++k) acc += bcastf(uv, k) * w2[k];

        eout[r * 64 + lane] = fmaxf(acc, 0.f);
    }
}

extern "C" void kernel_launch(void* const* d_in, const int* in_sizes, int n_in,
                              void* d_out, int out_size, void* d_ws, size_t ws_size,
                              hipStream_t stream) {
    // input order: contents0..8 = d_in[0..8], children0..7 = d_in[9..16],
    //              Wu = d_in[17], bu = d_in[18], Wh = d_in[19], bh = d_in[20]
    const float* Wu = (const float*)d_in[17];
    const float* bu = (const float*)d_in[18];
    const float* Wh = (const float*)d_in[19];
    const float* bh = (const float*)d_in[20];

    // workspace ping-pong: emb7 (256 MiB) in bufA, emb6 (128 MiB) in bufB, etc.
    float* bufA = (float*)d_ws;
    float* bufB = (float*)((char*)d_ws + (size_t)268435456);  // 256 MiB offset

    const float* ein = (const float*)d_in[8];  // contents8 for the fused leaf level
    for (int j = 7; j >= 0; --j) {
        const int n = in_sizes[j] / 32;        // rows at level j
        float* eout = (j == 0) ? (float*)d_out : ((j & 1) ? bufA : bufB);
        int blocks = n / WPB;
        if (blocks > 1024) blocks = 1024;
        const float* cont  = (const float*)d_in[j];
        const int*   child = (const int*)d_in[9 + j];
        if (j == 7)
            grnn_level<true><<<blocks, 256, 0, stream>>>(cont, child, ein, Wu, bu, Wh, bh, eout, n);
        else
            grnn_level<false><<<blocks, 256, 0, stream>>>(cont, child, ein, Wu, bu, Wh, bh, eout, n);
        ein = eout;
    }
}

// Round 2
// 701.653 us; speedup vs baseline: 3.5720x; 3.5720x over previous
//
#include <hip/hip_runtime.h>

typedef __attribute__((ext_vector_type(8))) short  short8;
typedef __attribute__((ext_vector_type(4))) float  f32x4;

#define MFMA16(A,B,C) __builtin_amdgcn_mfma_f32_16x16x32_bf16((A),(B),(C),0,0,0)

// split fp32 into bf16 hi + bf16 lo (x ~= hi + lo, residual < 2^-17 |x|)
__device__ __forceinline__ void splitf(float x, unsigned short &h, unsigned short &l) {
    unsigned u  = __float_as_uint(x);
    unsigned hu = (u + 0x8000u) & 0xFFFF0000u;
    h = (unsigned short)(hu >> 16);
    float r = x - __uint_as_float(hu);
    l = (unsigned short)((__float_as_uint(r) + 0x8000u) >> 16);
}

__device__ __forceinline__ void split8(const f32x4 a, const f32x4 b, short8 &h, short8 &l) {
#pragma unroll
    for (int i = 0; i < 4; ++i) {
        unsigned short hh, ll;
        splitf(a[i], hh, ll); h[i] = (short)hh; l[i] = (short)ll;
    }
#pragma unroll
    for (int i = 0; i < 4; ++i) {
        unsigned short hh, ll;
        splitf(b[i], hh, ll); h[4 + i] = (short)hh; l[4 + i] = (short)ll;
    }
}

// XOR-swizzled byte offset inside a [16 rows][64 bf16] plane (row stride 128B).
// Keeps 16B alignment; makes ds_read_b128 across rows bank-conflict-free (T2).
__device__ __forceinline__ unsigned swz(unsigned row, unsigned colbyte) {
    return row * 128u + (colbyte ^ ((row & 7u) << 4));
}

// One tree level. Each block: one 16-row tile per iteration; wave w owns output
// cols [16w,16w+16). Weights are held as B-fragments in registers (hi/lo).
// LEAF: children index contents8 (32-wide); u8 recomputed on the fly (fuses level 8).
template<bool LEAF>
__global__ __launch_bounds__(256, 4)
void grnn_mfma(const float* __restrict__ cont,   // ntiles*16 x 32
               const int*   __restrict__ child,  // ntiles*16 x 2
               const float* __restrict__ ein,    // emb_{j+1} (x64) or contents8 (x32)
               const float* __restrict__ Wu,     // 32 x 64
               const float* __restrict__ bu,     // 64
               const float* __restrict__ Wh,     // 192 x 64
               const float* __restrict__ bh,     // 64
               float* __restrict__ eout,         // ntiles*16 x 64
               int ntiles)
{
    __shared__ __align__(16) char lds[6 * 2048];  // planes: uL_hi,uL_lo,uR_hi,uR_lo,u_hi,u_lo

    const int lane = threadIdx.x & 63;
    const int w    = threadIdx.x >> 6;
    const int cidx = lane & 15;   // A-row / C-col index
    const int g    = lane >> 4;   // k-group

    // ---- weight B-fragments, hi/lo, resident in registers ----
    short8 WhH[6], WhL[6], WuH, WuL;
#pragma unroll
    for (int s = 0; s < 6; ++s) {
#pragma unroll
        for (int i = 0; i < 8; ++i) {
            unsigned short hh, ll;
            splitf(Wh[(32 * s + 8 * g + i) * 64 + 16 * w + cidx], hh, ll);
            WhH[s][i] = (short)hh; WhL[s][i] = (short)ll;
        }
    }
#pragma unroll
    for (int i = 0; i < 8; ++i) {
        unsigned short hh, ll;
        splitf(Wu[(8 * g + i) * 64 + 16 * w + cidx], hh, ll);
        WuH[i] = (short)hh; WuL[i] = (short)ll;
    }
    const float bul = bu[16 * w + cidx];
    const float bhl = bh[16 * w + cidx];

    for (int t = blockIdx.x; t < ntiles; t += gridDim.x) {
        const int r  = t * 16 + cidx;
        const int i0 = child[2 * r + 0];
        const int i1 = child[2 * r + 1];

        // issue gathers early (latency hides under u-GEMM + barrier)
        f32x4 gl[2][2][2];   // non-leaf: [side][kstep][half] emb rows (64 wide)
        f32x4 xl[2][2];      // leaf: [side][half] contents8 rows (32 wide)
        if (LEAF) {
            const f32x4* pL = (const f32x4*)(ein + (size_t)i0 * 32 + 8 * g);
            const f32x4* pR = (const f32x4*)(ein + (size_t)i1 * 32 + 8 * g);
            xl[0][0] = pL[0]; xl[0][1] = pL[1];
            xl[1][0] = pR[0]; xl[1][1] = pR[1];
        } else {
#pragma unroll
            for (int s = 0; s < 2; ++s) {
                const f32x4* pL = (const f32x4*)(ein + (size_t)i0 * 64 + 32 * s + 8 * g);
                const f32x4* pR = (const f32x4*)(ein + (size_t)i1 * 64 + 32 * s + 8 * g);
                gl[0][s][0] = pL[0]; gl[0][s][1] = pL[1];
                gl[1][s][0] = pR[0]; gl[1][s][1] = pR[1];
            }
        }
        const f32x4* pc = (const f32x4*)(cont + (size_t)r * 32 + 8 * g);
        const f32x4 ca = pc[0], cb = pc[1];

        // ---- phase 1: u tiles (K=32 GEMM), relu, stash in LDS ----
        short8 AH, AL;
        split8(ca, cb, AH, AL);
        f32x4 ua = {bul, bul, bul, bul};
        ua = MFMA16(AH, WuH, ua);
        ua = MFMA16(AH, WuL, ua);
        ua = MFMA16(AL, WuH, ua);

        f32x4 uLa, uRa;
        if (LEAF) {
            split8(xl[0][0], xl[0][1], AH, AL);
            uLa = {bul, bul, bul, bul};
            uLa = MFMA16(AH, WuH, uLa);
            uLa = MFMA16(AH, WuL, uLa);
            uLa = MFMA16(AL, WuH, uLa);
            split8(xl[1][0], xl[1][1], AH, AL);
            uRa = {bul, bul, bul, bul};
            uRa = MFMA16(AH, WuH, uRa);
            uRa = MFMA16(AH, WuL, uRa);
            uRa = MFMA16(AL, WuH, uRa);
        }

#pragma unroll
        for (int i = 0; i < 4; ++i) {
            const unsigned row = 4 * g + i;           // C-frag row
            const unsigned cb2 = 2u * (16 * w + cidx); // C-frag col (bytes)
            unsigned short hh, ll;
            splitf(fmaxf(ua[i], 0.f), hh, ll);
            *(unsigned short*)(lds + 4 * 2048 + swz(row, cb2)) = hh;
            *(unsigned short*)(lds + 5 * 2048 + swz(row, cb2)) = ll;
            if (LEAF) {
                splitf(fmaxf(uLa[i], 0.f), hh, ll);
                *(unsigned short*)(lds + 0 * 2048 + swz(row, cb2)) = hh;
                *(unsigned short*)(lds + 1 * 2048 + swz(row, cb2)) = ll;
                splitf(fmaxf(uRa[i], 0.f), hh, ll);
                *(unsigned short*)(lds + 2 * 2048 + swz(row, cb2)) = hh;
                *(unsigned short*)(lds + 3 * 2048 + swz(row, cb2)) = ll;
            }
        }
        __syncthreads();

        // ---- phase 2: emb = relu([hL|hR|u] @ Wh + bh) ----
        f32x4 acc = {bhl, bhl, bhl, bhl};
        if (LEAF) {
#pragma unroll
            for (int p = 0; p < 3; ++p) {
#pragma unroll
                for (int s = 0; s < 2; ++s) {
                    const short8 aH = *(const short8*)(lds + (2 * p + 0) * 2048 + swz(cidx, 64 * s + 16 * g));
                    const short8 aL = *(const short8*)(lds + (2 * p + 1) * 2048 + swz(cidx, 64 * s + 16 * g));
                    const int S = 2 * p + s;
                    acc = MFMA16(aH, WhH[S], acc);
                    acc = MFMA16(aH, WhL[S], acc);
                    acc = MFMA16(aL, WhH[S], acc);
                }
            }
        } else {
#pragma unroll
            for (int side = 0; side < 2; ++side) {
#pragma unroll
                for (int s = 0; s < 2; ++s) {
                    short8 aH, aL;
                    split8(gl[side][s][0], gl[side][s][1], aH, aL);
                    const int S = 2 * side + s;
                    acc = MFMA16(aH, WhH[S], acc);
                    acc = MFMA16(aH, WhL[S], acc);
                    acc = MFMA16(aL, WhH[S], acc);
                }
            }
#pragma unroll
            for (int s = 0; s < 2; ++s) {
                const short8 aH = *(const short8*)(lds + 4 * 2048 + swz(cidx, 64 * s + 16 * g));
                const short8 aL = *(const short8*)(lds + 5 * 2048 + swz(cidx, 64 * s + 16 * g));
                const int S = 4 + s;
                acc = MFMA16(aH, WhH[S], acc);
                acc = MFMA16(aH, WhL[S], acc);
                acc = MFMA16(aL, WhH[S], acc);
            }
        }

#pragma unroll
        for (int i = 0; i < 4; ++i)
            eout[(size_t)(t * 16 + 4 * g + i) * 64 + 16 * w + cidx] = fmaxf(acc[i], 0.f);
        __syncthreads();
    }
}

extern "C" void kernel_launch(void* const* d_in, const int* in_sizes, int n_in,
                              void* d_out, int out_size, void* d_ws, size_t ws_size,
                              hipStream_t stream) {
    // inputs: contents0..8 = d_in[0..8], children0..7 = d_in[9..16],
    //         Wu = d_in[17], bu = d_in[18], Wh = d_in[19], bh = d_in[20]
    const float* Wu = (const float*)d_in[17];
    const float* bu = (const float*)d_in[18];
    const float* Wh = (const float*)d_in[19];
    const float* bh = (const float*)d_in[20];

    float* bufA = (float*)d_ws;                               // emb7/5/3/1 (max 256 MiB)
    float* bufB = (float*)((char*)d_ws + (size_t)268435456);  // emb6/4/2

    const float* ein = (const float*)d_in[8];  // contents8 for fused leaf
    for (int j = 7; j >= 0; --j) {
        const int n      = in_sizes[j] / 32;
        const int ntiles = n / 16;
        float* eout = (j == 0) ? (float*)d_out : ((j & 1) ? bufA : bufB);
        int blocks = ntiles < 4096 ? ntiles : 4096;
        const float* cont  = (const float*)d_in[j];
        const int*   child = (const int*)d_in[9 + j];
        if (j == 7)
            grnn_mfma<true><<<blocks, 256, 0, stream>>>(cont, child, ein, Wu, bu, Wh, bh, eout, ntiles);
        else
            grnn_mfma<false><<<blocks, 256, 0, stream>>>(cont, child, ein, Wu, bu, Wh, bh, eout, ntiles);
        ein = eout;
    }
}

// Round 3
// 682.095 us; speedup vs baseline: 3.6744x; 1.0287x over previous
//
#include <hip/hip_runtime.h>

typedef __attribute__((ext_vector_type(8))) short  short8;
typedef __attribute__((ext_vector_type(4))) float  f32x4;

#define MFMA16(A,B,C) __builtin_amdgcn_mfma_f32_16x16x32_bf16((A),(B),(C),0,0,0)

// split fp32 into bf16 hi + bf16 lo (x ~= hi + lo, residual < 2^-17 |x|)
__device__ __forceinline__ void splitf(float x, unsigned short &h, unsigned short &l) {
    unsigned u  = __float_as_uint(x);
    unsigned hu = (u + 0x8000u) & 0xFFFF0000u;
    h = (unsigned short)(hu >> 16);
    float r = x - __uint_as_float(hu);
    l = (unsigned short)((__float_as_uint(r) + 0x8000u) >> 16);
}

__device__ __forceinline__ void split8(const f32x4 a, const f32x4 b, short8 &h, short8 &l) {
#pragma unroll
    for (int i = 0; i < 4; ++i) {
        unsigned short hh, ll;
        splitf(a[i], hh, ll); h[i] = (short)hh; l[i] = (short)ll;
    }
#pragma unroll
    for (int i = 0; i < 4; ++i) {
        unsigned short hh, ll;
        splitf(b[i], hh, ll); h[4 + i] = (short)hh; l[4 + i] = (short)ll;
    }
}

// XOR-swizzled byte offset inside a [16 rows][64 bf16] plane (row stride 128B).
__device__ __forceinline__ unsigned swz(unsigned row, unsigned colbyte) {
    return row * 128u + (colbyte ^ ((row & 7u) << 4));
}

// One tree level. Block = 4 waves; wave w owns output cols [16w,16w+16).
// Weights resident in registers as hi/lo B-fragments.
// LEAF:  children gather contents8 (fp32, 32-wide); u8 recomputed on the fly.
// !LEAF: children gather emb_{j+1} stored as bf16 hi/lo planes (256B/row) ->
//        fragments feed MFMA directly, no split.
// FINAL: output fp32 to d_out; else output hi/lo planes.
template<bool LEAF, bool FINAL>
__global__ __launch_bounds__(256, 4)
void grnn_mfma(const float* __restrict__ cont,   // ntiles*16 x 32 (fp32)
               const int*   __restrict__ child,  // ntiles*16 x 2
               const void*  __restrict__ ein_,   // emb_{j+1} hi/lo planes or contents8 fp32
               const float* __restrict__ Wu,     // 32 x 64
               const float* __restrict__ bu,     // 64
               const float* __restrict__ Wh,     // 192 x 64
               const float* __restrict__ bh,     // 64
               void*        __restrict__ eout_,  // hi/lo planes (or fp32 if FINAL)
               int ntiles)
{
    constexpr int NP = LEAF ? 6 : 2;              // planes per buffer
    __shared__ __align__(16) char lds[NP * 2 * 2048];  // double-buffered

    const int lane = threadIdx.x & 63;
    const int w    = threadIdx.x >> 6;
    const int cidx = lane & 15;   // A-row / C-col index
    const int g    = lane >> 4;   // k-group

    // ---- weight B-fragments, hi/lo, resident in registers ----
    short8 WhH[6], WhL[6], WuH, WuL;
#pragma unroll
    for (int s = 0; s < 6; ++s) {
#pragma unroll
        for (int i = 0; i < 8; ++i) {
            unsigned short hh, ll;
            splitf(Wh[(32 * s + 8 * g + i) * 64 + 16 * w + cidx], hh, ll);
            WhH[s][i] = (short)hh; WhL[s][i] = (short)ll;
        }
    }
#pragma unroll
    for (int i = 0; i < 8; ++i) {
        unsigned short hh, ll;
        splitf(Wu[(8 * g + i) * 64 + 16 * w + cidx], hh, ll);
        WuH[i] = (short)hh; WuL[i] = (short)ll;
    }
    const float bul = bu[16 * w + cidx];
    const float bhl = bh[16 * w + cidx];

    int p = 0;
    for (int t = blockIdx.x; t < ntiles; t += gridDim.x, p ^= 1) {
        const int r = t * 16 + cidx;
        const int2 ch = *(const int2*)(child + 2 * r);

        // ---- issue gathers first (latency hides under phase 1 + barrier) ----
        short8 gh[2][2], glo[2][2];   // !LEAF: [side][kstep] hi/lo fragments
        f32x4  xl[2][2];              // LEAF:  [side][half] contents8 fp32
        if (LEAF) {
            const float* e = (const float*)ein_;
            const f32x4* pL = (const f32x4*)(e + (size_t)ch.x * 32 + 8 * g);
            const f32x4* pR = (const f32x4*)(e + (size_t)ch.y * 32 + 8 * g);
            xl[0][0] = pL[0]; xl[0][1] = pL[1];
            xl[1][0] = pR[0]; xl[1][1] = pR[1];
        } else {
            const unsigned short* e = (const unsigned short*)ein_;
            const unsigned short* pL = e + (size_t)ch.x * 128 + 8 * g;
            const unsigned short* pR = e + (size_t)ch.y * 128 + 8 * g;
#pragma unroll
            for (int s = 0; s < 2; ++s) {
                gh [0][s] = *(const short8*)(pL + 32 * s);
                glo[0][s] = *(const short8*)(pL + 64 + 32 * s);
                gh [1][s] = *(const short8*)(pR + 32 * s);
                glo[1][s] = *(const short8*)(pR + 64 + 32 * s);
            }
        }
        const f32x4* pc = (const f32x4*)(cont + (size_t)r * 32 + 8 * g);
        const f32x4 ca = pc[0], cb = pc[1];

        // ---- phase 1: u tiles (K=32), relu, split, stash in LDS buf p ----
        char* base = lds + p * (NP * 2048);
        short8 AH, AL;
        split8(ca, cb, AH, AL);
        f32x4 ua = {bul, bul, bul, bul};
        ua = MFMA16(AH, WuH, ua);
        ua = MFMA16(AH, WuL, ua);
        ua = MFMA16(AL, WuH, ua);

        f32x4 uLa, uRa;
        if (LEAF) {
            split8(xl[0][0], xl[0][1], AH, AL);
            uLa = {bul, bul, bul, bul};
            uLa = MFMA16(AH, WuH, uLa);
            uLa = MFMA16(AH, WuL, uLa);
            uLa = MFMA16(AL, WuH, uLa);
            split8(xl[1][0], xl[1][1], AH, AL);
            uRa = {bul, bul, bul, bul};
            uRa = MFMA16(AH, WuH, uRa);
            uRa = MFMA16(AH, WuL, uRa);
            uRa = MFMA16(AL, WuH, uRa);
        }

        const unsigned cb2 = 2u * (16 * w + cidx);
#pragma unroll
        for (int i = 0; i < 4; ++i) {
            const unsigned row = 4 * g + i;
            unsigned short hh, ll;
            splitf(fmaxf(ua[i], 0.f), hh, ll);
            *(unsigned short*)(base + (NP - 2) * 2048 + swz(row, cb2)) = hh;
            *(unsigned short*)(base + (NP - 1) * 2048 + swz(row, cb2)) = ll;
            if (LEAF) {
                splitf(fmaxf(uLa[i], 0.f), hh, ll);
                *(unsigned short*)(base + 0 * 2048 + swz(row, cb2)) = hh;
                *(unsigned short*)(base + 1 * 2048 + swz(row, cb2)) = ll;
                splitf(fmaxf(uRa[i], 0.f), hh, ll);
                *(unsigned short*)(base + 2 * 2048 + swz(row, cb2)) = hh;
                *(unsigned short*)(base + 3 * 2048 + swz(row, cb2)) = ll;
            }
        }
        __syncthreads();   // single barrier per tile (double-buffered planes)

        // ---- phase 2: emb = relu([hL|hR|u] @ Wh + bh) ----
        f32x4 acc = {bhl, bhl, bhl, bhl};
        if (LEAF) {
#pragma unroll
            for (int q = 0; q < 3; ++q) {
#pragma unroll
                for (int s = 0; s < 2; ++s) {
                    const short8 aH = *(const short8*)(base + (2 * q + 0) * 2048 + swz(cidx, 64 * s + 16 * g));
                    const short8 aL = *(const short8*)(base + (2 * q + 1) * 2048 + swz(cidx, 64 * s + 16 * g));
                    const int S = 2 * q + s;
                    acc = MFMA16(aH, WhH[S], acc);
                    acc = MFMA16(aH, WhL[S], acc);
                    acc = MFMA16(aL, WhH[S], acc);
                }
            }
        } else {
#pragma unroll
            for (int side = 0; side < 2; ++side) {
#pragma unroll
                for (int s = 0; s < 2; ++s) {
                    const int S = 2 * side + s;
                    acc = MFMA16(gh [side][s], WhH[S], acc);
                    acc = MFMA16(gh [side][s], WhL[S], acc);
                    acc = MFMA16(glo[side][s], WhH[S], acc);
                }
            }
#pragma unroll
            for (int s = 0; s < 2; ++s) {
                const short8 aH = *(const short8*)(base + 0 * 2048 + swz(cidx, 64 * s + 16 * g));
                const short8 aL = *(const short8*)(base + 1 * 2048 + swz(cidx, 64 * s + 16 * g));
                const int S = 4 + s;
                acc = MFMA16(aH, WhH[S], acc);
                acc = MFMA16(aH, WhL[S], acc);
                acc = MFMA16(aL, WhH[S], acc);
            }
        }

        // ---- store ----
        if (FINAL) {
            float* out = (float*)eout_;
#pragma unroll
            for (int i = 0; i < 4; ++i)
                out[(size_t)(t * 16 + 4 * g + i) * 64 + 16 * w + cidx] = fmaxf(acc[i], 0.f);
        } else {
            unsigned short* out = (unsigned short*)eout_;
#pragma unroll
            for (int i = 0; i < 4; ++i) {
                unsigned short hh, ll;
                splitf(fmaxf(acc[i], 0.f), hh, ll);
                const size_t rb = (size_t)(t * 16 + 4 * g + i) * 128;
                out[rb + 16 * w + cidx]      = hh;
                out[rb + 64 + 16 * w + cidx] = ll;
            }
        }
    }
}

extern "C" void kernel_launch(void* const* d_in, const int* in_sizes, int n_in,
                              void* d_out, int out_size, void* d_ws, size_t ws_size,
                              hipStream_t stream) {
    // inputs: contents0..8 = d_in[0..8], children0..7 = d_in[9..16],
    //         Wu = d_in[17], bu = d_in[18], Wh = d_in[19], bh = d_in[20]
    const float* Wu = (const float*)d_in[17];
    const float* bu = (const float*)d_in[18];
    const float* Wh = (const float*)d_in[19];
    const float* bh = (const float*)d_in[20];

    // emb_j stored as bf16 hi/lo planes, 256B/row -> same footprint as fp32
    void* bufA = d_ws;                               // emb7/5/3/1 (max 256 MiB)
    void* bufB = (char*)d_ws + (size_t)268435456;    // emb6/4/2

    const void* ein = d_in[8];  // contents8 (fp32) for the fused leaf level
    for (int j = 7; j >= 0; --j) {
        const int n      = in_sizes[j] / 32;
        const int ntiles = n / 16;
        void* eout = (j == 0) ? d_out : ((j & 1) ? bufA : bufB);
        int blocks = ntiles < 4096 ? ntiles : 4096;
        const float* cont  = (const float*)d_in[j];
        const int*   child = (const int*)d_in[9 + j];
        if (j == 7)
            grnn_mfma<true,  false><<<blocks, 256, 0, stream>>>(cont, child, ein, Wu, bu, Wh, bh, eout, ntiles);
        else if (j == 0)
            grnn_mfma<false, true ><<<blocks, 256, 0, stream>>>(cont, child, ein, Wu, bu, Wh, bh, eout, ntiles);
        else
            grnn_mfma<false, false><<<blocks, 256, 0, stream>>>(cont, child, ein, Wu, bu, Wh, bh, eout, ntiles);
        ein = eout;
    }
}